// Round 5
// baseline (299.644 us; speedup 1.0000x reference)
//
#include <hip/hip_runtime.h>

#define N_NODES 50000
#define N_PAD   50048
#define N_EDGES 800000
#define NBE     3125    // edge blocks
#define NB_IL   6250    // interleave blocks (N_NODES*32/256)

typedef __attribute__((ext_vector_type(8))) short bf16x8;
typedef __attribute__((ext_vector_type(4))) float f32x4;

__device__ __forceinline__ unsigned short f2bf(float f) {
    unsigned u = __float_as_uint(f);
    u = (u + 0x7fffu + ((u >> 16) & 1u)) >> 16;
    return (unsigned short)u;
}

__device__ __forceinline__ float fsig(float x) {
    x = fminf(fmaxf(x, -30.f), 30.f);
    float t = __expf(x);
    return __fdividef(t, 1.f + t);
}
__device__ __forceinline__ float ftanh(float x) {
    x = fminf(fmaxf(x, -15.f), 15.f);
    float t = __expf(2.f * x);
    return 1.f - __fdividef(2.f, t + 1.f);
}

__device__ __forceinline__ unsigned xcd_id() {
    unsigned x;
    asm volatile("s_getreg_b32 %0, hwreg(HW_REG_XCC_ID)" : "=s"(x));
    return x & 7;
}

// per-block int32/int64 detect: int64 edge_index => odd 32-bit words all zero
__device__ __forceinline__ int block_is_i32(const int* __restrict__ eiv, int t, int* sflag) {
    if (t == 0) *sflag = 0;
    __syncthreads();
    int v = eiv[1 + 2 * t];
    if (v) atomicOr(sflag, 1);
    __syncthreads();
    return *sflag;
}

// ---------------------------------------------------------------- merged: deg_rank || interleave || wprep
// deg_rank: per-XCD replicated bins, workgroup-scope u64 atomic -> stays in XCD-local L2
// (replica k only ever touched from XCD k; dispatch-end L2 writeback publishes to scan1).
// hi32 = count (old value = rank within (row,rep)), lo32 = fixed-point 2^-22 weighted degree.

__global__ __launch_bounds__(256) void k_deg_prep(
    const void* __restrict__ eiraw, const float* __restrict__ w,
    unsigned long long* __restrict__ packed8, unsigned short* __restrict__ rank,
    const float* __restrict__ X, const float* __restrict__ H, unsigned short* __restrict__ XH,
    const float* __restrict__ Wxi, const float* __restrict__ Whi,
    const float* __restrict__ Wxf, const float* __restrict__ Whf,
    const float* __restrict__ Wxc, const float* __restrict__ Whc,
    const float* __restrict__ Wxo, const float* __restrict__ Who,
    const float* __restrict__ bxi, const float* __restrict__ bhi,
    const float* __restrict__ bxf, const float* __restrict__ bhf,
    const float* __restrict__ bxc, const float* __restrict__ bhc,
    const float* __restrict__ bxo, const float* __restrict__ bho,
    const float* __restrict__ bgi, const float* __restrict__ bgf,
    const float* __restrict__ bgc, const float* __restrict__ bgo,
    unsigned short* __restrict__ Wf, float* __restrict__ ball) {
    __shared__ int sflag;
    int b = blockIdx.x, t = threadIdx.x;
    if (b < NBE) {
        int is32 = block_is_i32((const int*)eiraw, t, &sflag);
        int e = b * 256 + t;
        if (e >= N_EDGES) return;
        int r = is32 ? ((const int*)eiraw)[e] : (int)(((const long long*)eiraw)[e]);
        unsigned rep = xcd_id();
        unsigned qw = (unsigned)(w[e] * 4194304.f + 0.5f);
        unsigned long long old = __hip_atomic_fetch_add(
            &packed8[(size_t)rep * N_NODES + r], (1ull << 32) | (unsigned long long)qw,
            __ATOMIC_RELAXED, __HIP_MEMORY_SCOPE_WORKGROUP);
        rank[e] = (unsigned short)(((old >> 32) & 255u) | (rep << 8));
        return;
    }
    int bb = b - NBE;
    if (bb < NB_IL) {
        int tt = bb * 256 + t;                   // one thread per 4 channels
        int node = tt >> 5, g = tt & 31;
        float4 v = (g < 16) ? *(const float4*)(X + (size_t)node * 64 + g * 4)
                            : *(const float4*)(H + (size_t)node * 64 + (g - 16) * 4);
        ushort4 o;
        o.x = f2bf(v.x); o.y = f2bf(v.y); o.z = f2bf(v.z); o.w = f2bf(v.w);
        *(ushort4*)(XH + (size_t)node * 128 + g * 4) = o;
        return;
    }
    bb -= NB_IL;
    if (bb < 48) {
        // Wf layout: [ks(12)][nt(16)][lane(64)][j(8)] bf16; T0=V,T1=-U1,T2=2U2-V fold
        int flat = bb * 256 + t;
        int l = flat & 63, nt = (flat >> 6) & 15, ks = flat >> 10;
        int n = nt * 16 + (l & 15);
        int g = n >> 6, c = n & 63;
        const float* WX = (g == 0) ? Wxi : (g == 1) ? Wxf : (g == 2) ? Wxc : Wxo;
        const float* WH = (g == 0) ? Whi : (g == 1) ? Whf : (g == 2) ? Whc : Who;
        int k0 = ks * 32 + (l >> 4) * 8;
        unsigned short ov[8];
#pragma unroll
        for (int j = 0; j < 8; j++) {
            int k = k0 + j;
            int bsel = k >> 7, ch = k & 127;
            const float* W = (ch < 64) ? WX : WH;
            int kk = ch & 63;
            float v;
            if (bsel == 0)      v = W[kk * 64 + c] - W[2 * 4096 + kk * 64 + c];
            else if (bsel == 1) v = -W[4096 + kk * 64 + c];
            else                v = 2.f * W[2 * 4096 + kk * 64 + c];
            ov[j] = f2bf(v);
        }
        uint4 o;
        o.x = (unsigned)ov[0] | ((unsigned)ov[1] << 16);
        o.y = (unsigned)ov[2] | ((unsigned)ov[3] << 16);
        o.z = (unsigned)ov[4] | ((unsigned)ov[5] << 16);
        o.w = (unsigned)ov[6] | ((unsigned)ov[7] << 16);
        *(uint4*)(Wf + (size_t)flat * 8) = o;
    } else {
        int g = t >> 6, c = t & 63;
        const float* BX = (g == 0) ? bxi : (g == 1) ? bxf : (g == 2) ? bxc : bxo;
        const float* BH = (g == 0) ? bhi : (g == 1) ? bhf : (g == 2) ? bhc : bho;
        const float* BG = (g == 0) ? bgi : (g == 1) ? bgf : (g == 2) ? bgc : bgo;
        ball[t] = BX[c] + BH[c] + BG[c];
    }
}

// ---------------------------------------------------------------- scans
// rp stays block-partial (part added downstream). Per-node per-replica bases packed 8xu8 in u64.

__global__ __launch_bounds__(256) void k_scan1(const unsigned long long* __restrict__ packed8,
                                               int* __restrict__ rp, int* __restrict__ part,
                                               float* __restrict__ dinv,
                                               unsigned long long* __restrict__ baserep) {
    __shared__ int s[256];
    int t = threadIdx.x, i = blockIdx.x * 256 + t;
    int cnt = 0;
    unsigned long long baseq = 0, sumw = 0;
    if (i < N_NODES) {
#pragma unroll
        for (int r = 0; r < 8; r++) {
            unsigned long long p = packed8[(size_t)r * N_NODES + i];
            baseq |= ((unsigned long long)(cnt & 255)) << (8 * r);
            cnt += (int)(p >> 32);
            sumw += (p & 0xffffffffull);
        }
    }
    s[t] = cnt; __syncthreads();
    for (int d = 1; d < 256; d <<= 1) {
        int add = (t >= d) ? s[t - d] : 0;
        __syncthreads();
        s[t] += add;
        __syncthreads();
    }
    if (i < N_NODES) {
        rp[i] = s[t] - cnt;                       // exclusive within block
        baserep[i] = baseq;
        float dg = (float)sumw * (1.f / 4194304.f);
        dinv[i] = (dg > 0.f) ? rsqrtf(dg) : 0.f;
        if (i == N_NODES - 1) rp[N_NODES] = s[t];
    }
    if (t == 255) part[blockIdx.x] = s[255];
}

__global__ __launch_bounds__(256) void k_scan2(int* __restrict__ part, int nb) {
    __shared__ int s[256];
    int t = threadIdx.x;
    int v = (t < nb) ? part[t] : 0;
    s[t] = v; __syncthreads();
    for (int d = 1; d < 256; d <<= 1) {
        int add = (t >= d) ? s[t - d] : 0;
        __syncthreads();
        s[t] += add;
        __syncthreads();
    }
    if (t < nb) part[t] = s[t] - v;
}

// atomic-free scatter: pos = rp[r] + part[r>>8] + base8[r][rep] + rank
__global__ __launch_bounds__(256) void k_scatter(const void* __restrict__ eiraw, const float* __restrict__ w,
                                                 const unsigned short* __restrict__ rank,
                                                 const float* __restrict__ dinv, const int* __restrict__ rp,
                                                 const int* __restrict__ part,
                                                 const unsigned long long* __restrict__ baserep,
                                                 int* __restrict__ colp, float* __restrict__ nwp) {
    __shared__ int sflag;
    int t = threadIdx.x;
    int is32 = block_is_i32((const int*)eiraw, t, &sflag);
    int e = blockIdx.x * 256 + t;
    if (e >= N_EDGES) return;
    int r, c;
    if (is32) { r = ((const int*)eiraw)[e]; c = ((const int*)eiraw)[N_EDGES + e]; }
    else      { r = (int)(((const long long*)eiraw)[e]); c = (int)(((const long long*)eiraw)[N_EDGES + e]); }
    unsigned rr = rank[e];
    int rep = rr >> 8, rk = rr & 255;
    int base = (int)((baserep[r] >> (8 * rep)) & 255u);
    int pos = rp[r] + part[r >> 8] + base + rk;
    colp[pos] = c;
    nwp[pos] = dinv[r] * w[e] * dinv[c];
}

// ---------------------------------------------------------------- SpMV: dst = A*src (bf16, fp32 accum)
// one wave per node; lane = channel pair; masked 8-edge groups keep 8 gathers in flight.

__global__ __launch_bounds__(256) void k_spmv_bf(const unsigned short* __restrict__ src,
                                                 unsigned short* __restrict__ dst,
                                                 const int* __restrict__ rp, const int* __restrict__ part,
                                                 const int* __restrict__ colp, const float* __restrict__ nwp) {
    int wid = threadIdx.x >> 6, lane = threadIdx.x & 63;
    int node = blockIdx.x * 4 + wid;
    if (node >= N_NODES) return;
    int s = rp[node] + part[node >> 8];
    int e = rp[node + 1] + part[(node + 1) >> 8];
    float a0 = 0.f, a1 = 0.f;
    for (int jb = s; jb < e; jb += 8) {
        int   c[8]; float wv[8]; unsigned vv[8];
#pragma unroll
        for (int k = 0; k < 8; k++) {
            int j = jb + k;
            int jc = (j < e) ? j : (e - 1);
            c[k]  = colp[jc];
            wv[k] = (j < e) ? nwp[jc] : 0.f;
        }
#pragma unroll
        for (int k = 0; k < 8; k++)
            vv[k] = *(const unsigned*)(src + (size_t)c[k] * 128 + lane * 2);
#pragma unroll
        for (int k = 0; k < 8; k++) {
            a0 = fmaf(wv[k], __uint_as_float(vv[k] << 16), a0);
            a1 = fmaf(wv[k], __uint_as_float(vv[k] & 0xffff0000u), a1);
        }
    }
    unsigned o = (unsigned)f2bf(a0) | ((unsigned)f2bf(a1) << 16);
    *(unsigned*)(dst + (size_t)node * 128 + lane * 2) = o;
}

// ---------------------------------------------------------------- MFMA GEMM [50000,384]@[384,256] + LSTM gates
// block = 4 waves; wave = 16 rows x 256 cols (16 acc tiles). A direct global b128; B double-buffered LDS,
// one barrier per k-step (barrier's lgkmcnt drain orders reads of buf[k&1] before stores at k+2).

__global__ __launch_bounds__(256) void k_gemm_mfma(
    const unsigned short* __restrict__ XH, const unsigned short* __restrict__ U1,
    const unsigned short* __restrict__ U2, const unsigned short* __restrict__ Wf,
    const float* __restrict__ ball, const float* __restrict__ C, float* __restrict__ out) {
    __shared__ __align__(16) uint4 Bs[2][1024];   // 2 x 16 KB

    int t = threadIdx.x;
    int wid = t >> 6, lane = t & 63;
    int col = lane & 15, quad = lane >> 4;
    int m0 = blockIdx.x * 64 + wid * 16;
    int arow = m0 + col;

    f32x4 acc[16];
#pragma unroll
    for (int i = 0; i < 16; i++) acc[i] = (f32x4){0.f, 0.f, 0.f, 0.f};

    const unsigned short* srcs[3] = {XH, U1, U2};

    bf16x8 a_cur = *(const bf16x8*)(srcs[0] + (size_t)arow * 128 + quad * 8);
    const uint4* g0 = (const uint4*)Wf;
    uint4 p0 = g0[t], p1 = g0[t + 256], p2 = g0[t + 512], p3 = g0[t + 768];

    for (int ks = 0; ks < 12; ks++) {
        uint4* dstb = Bs[ks & 1];
        dstb[t] = p0; dstb[t + 256] = p1; dstb[t + 512] = p2; dstb[t + 768] = p3;
        __syncthreads();
        bf16x8 a_nxt = a_cur;
        if (ks < 11) {
            int ks1 = ks + 1;
            const uint4* g = (const uint4*)(Wf + (size_t)ks1 * 8192);
            p0 = g[t]; p1 = g[t + 256]; p2 = g[t + 512]; p3 = g[t + 768];
            a_nxt = *(const bf16x8*)(srcs[ks1 >> 2] + (size_t)arow * 128 + (ks1 & 3) * 32 + quad * 8);
        }
        const unsigned short* B = (const unsigned short*)Bs[ks & 1];
#pragma unroll
        for (int nt = 0; nt < 16; nt++) {
            bf16x8 bfrag = *(const bf16x8*)(B + nt * 512 + lane * 8);
            acc[nt] = __builtin_amdgcn_mfma_f32_16x16x32_bf16(a_cur, bfrag, acc[nt], 0, 0, 0);
        }
        a_cur = a_nxt;
    }

    // epilogue: acc[g*4+cq][r] = pre-act of gate g, node m0+quad*4+r, channel cq*16+col
    float bI[4], bF[4], bT[4], bO[4];
#pragma unroll
    for (int cq = 0; cq < 4; cq++) {
        int c = cq * 16 + col;
        bI[cq] = ball[c]; bF[cq] = ball[64 + c]; bT[cq] = ball[128 + c]; bO[cq] = ball[192 + c];
    }
#pragma unroll
    for (int r = 0; r < 4; r++) {
        int node = m0 + quad * 4 + r;
        if (node >= N_NODES) continue;
#pragma unroll
        for (int cq = 0; cq < 4; cq++) {
            int c = cq * 16 + col;
            float ig = fsig(acc[0 + cq][r]  + bI[cq]);
            float fg = fsig(acc[4 + cq][r]  + bF[cq]);
            float tg = ftanh(acc[8 + cq][r] + bT[cq]);
            float og = fsig(acc[12 + cq][r] + bO[cq]);
            float cv = fmaf(fg, C[(size_t)node * 64 + c], ig * tg);
            out[(size_t)node * 64 + c] = og * ftanh(cv);
            out[(size_t)N_NODES * 64 + (size_t)node * 64 + c] = cv;
        }
    }
}

// ---------------------------------------------------------------- launch

extern "C" void kernel_launch(void* const* d_in, const int* in_sizes, int n_in,
                              void* d_out, int out_size, void* d_ws, size_t ws_size,
                              hipStream_t stream) {
    const float* X   = (const float*)d_in[0];
    const void*  ei  = d_in[1];
    const float* w   = (const float*)d_in[2];
    const float* H   = (const float*)d_in[3];
    const float* C   = (const float*)d_in[4];
    const float* Wxi = (const float*)d_in[5];  const float* bxi = (const float*)d_in[6];
    const float* Whi = (const float*)d_in[7];  const float* bhi = (const float*)d_in[8];
    const float* Wxf = (const float*)d_in[9];  const float* bxf = (const float*)d_in[10];
    const float* Whf = (const float*)d_in[11]; const float* bhf = (const float*)d_in[12];
    const float* Wxc = (const float*)d_in[13]; const float* bxc = (const float*)d_in[14];
    const float* Whc = (const float*)d_in[15]; const float* bhc = (const float*)d_in[16];
    const float* Wxo = (const float*)d_in[17]; const float* bxo = (const float*)d_in[18];
    const float* Who = (const float*)d_in[19]; const float* bho = (const float*)d_in[20];
    const float* bgi = (const float*)d_in[21]; const float* bgf = (const float*)d_in[22];
    const float* bgc = (const float*)d_in[23]; const float* bgo = (const float*)d_in[24];
    float* out = (float*)d_out;

    char* ws = (char*)d_ws;
    size_t off = 0;
    auto alloc = [&](size_t bytes) -> char* {
        char* p = ws + off;
        off = (off + bytes + 255) & ~(size_t)255;
        return p;
    };
    unsigned long long* packed8 = (unsigned long long*)alloc((size_t)8 * N_NODES * 8);
    unsigned long long* baserep = (unsigned long long*)alloc((size_t)N_NODES * 8);
    unsigned short* rank = (unsigned short*)alloc((size_t)N_EDGES * 2);
    int*   rp   = (int*)alloc((N_NODES + 1) * 4);
    int*   part = (int*)alloc(256 * 4);
    float* dinv = (float*)alloc(N_NODES * 4);
    int*   colp = (int*)alloc((size_t)(N_EDGES + 8) * 4);
    float* nwp  = (float*)alloc((size_t)(N_EDGES + 8) * 4);
    unsigned short* XH = (unsigned short*)alloc((size_t)N_PAD * 128 * 2);
    unsigned short* U1 = (unsigned short*)alloc((size_t)N_PAD * 128 * 2);
    unsigned short* U2 = (unsigned short*)alloc((size_t)N_PAD * 128 * 2);
    unsigned short* Wf = (unsigned short*)alloc((size_t)12 * 16 * 64 * 8 * 2);
    float* ball = (float*)alloc(256 * 4);
    (void)ws_size; (void)in_sizes; (void)n_in; (void)out_size;

    hipMemsetAsync(packed8, 0, (size_t)8 * N_NODES * 8, stream);

    int nbN = (N_NODES + 255) / 256;

    k_deg_prep<<<NBE + NB_IL + 49, 256, 0, stream>>>(ei, w, packed8, rank, X, H, XH,
                                                     Wxi, Whi, Wxf, Whf, Wxc, Whc, Wxo, Who,
                                                     bxi, bhi, bxf, bhf, bxc, bhc, bxo, bho,
                                                     bgi, bgf, bgc, bgo, Wf, ball);
    k_scan1<<<nbN, 256, 0, stream>>>(packed8, rp, part, dinv, baserep);
    k_scan2<<<1, 256, 0, stream>>>(part, nbN);
    k_scatter<<<NBE, 256, 0, stream>>>(ei, w, rank, dinv, rp, part, baserep, colp, nwp);
    k_spmv_bf<<<(N_NODES + 3) / 4, 256, 0, stream>>>(XH, U1, rp, part, colp, nwp);
    k_spmv_bf<<<(N_NODES + 3) / 4, 256, 0, stream>>>(U1, U2, rp, part, colp, nwp);
    k_gemm_mfma<<<(N_NODES + 63) / 64, 256, 0, stream>>>(XH, U1, U2, Wf, ball, C, out);
}